// Round 11
// baseline (203.830 us; speedup 1.0000x reference)
//
#include <hip/hip_runtime.h>
#include <math.h>

#define NT 32768
#define DIM 256
#define NE 16
#define EH 128
#define RH 64
#define TB 64
#define NPERS 512

// ws layout: float part1[NT*DIM] first, then int/float bookkeeping, then bf16 weights, then xg
#define IB (NT * DIM)
#define WS_COUNTS (IB)
#define WS_OFFSETS (IB + 16)
#define WS_CURSORS (IB + 33)
#define WS_NBLK (IB + 49)
#define WS_TABLE (IB + 64)
#define WS_TOKE (IB + 4096)
#define WS_LIST (WS_TOKE + 2 * NT)
#define WS_TOKG (WS_LIST + 2 * NT)
#define WS_LIST_G (WS_TOKG + 2 * NT)
#define WS_END_I (WS_LIST_G + 2 * NT)
// ushort-unit offsets for bf16 transposed weights + gathered x
#define U_W1T (2 * WS_END_I)
#define U_W2T (U_W1T + NE * DIM * EH)
#define U_XG (U_W2T + NE * DIM * EH)

typedef __attribute__((ext_vector_type(4))) float f32x4;
typedef __attribute__((ext_vector_type(8))) short bf16x8;
typedef __attribute__((ext_vector_type(8))) unsigned short us8;

// XOR swizzles: SWZ9 for 512B-stride tiles, SWZ8 for 256B-stride tiles
#define SWZ9(b) ((b) ^ (((b) >> 5) & 0x70))
#define SWZ8(b) ((b) ^ (((b) >> 4) & 0x70))

__device__ inline unsigned short f2bf(float f) {
    unsigned int bits = __builtin_bit_cast(unsigned int, f);
    bits += 0x7fffu + ((bits >> 16) & 1u);   // RNE
    return (unsigned short)(bits >> 16);
}

__device__ inline float fast_tanh(float v) {
    float cv = fminf(fmaxf(v, -15.f), 15.f);
    float ex = __expf(2.f * cv);
    return (ex - 1.f) / (ex + 1.f);
}

// ---------------- Router ----------------
__global__ __launch_bounds__(256) void router_kernel(
    const float* __restrict__ x,
    const float* __restrict__ rw1, const float* __restrict__ rb1,
    const float* __restrict__ rw2, const float* __restrict__ rb2,
    float* __restrict__ w_out, int* __restrict__ wsi, float* __restrict__ wsf)
{
    __shared__ float xT[64][68];
    __shared__ float w1s[64][64];
    __shared__ float hs[64][68];
    __shared__ float ls[64][20];
    __shared__ int scnt[16];

    const int tid = threadIdx.x;
    const int tok0 = blockIdx.x * 64;
    if (tid < 16) scnt[tid] = 0;

    float acc[4][4];
#pragma unroll
    for (int i = 0; i < 4; ++i)
#pragma unroll
        for (int j = 0; j < 4; ++j) acc[i][j] = 0.f;

    const int tt = (tid & 15) * 4;
    const int hh = (tid >> 4) * 4;

    for (int kc = 0; kc < 4; ++kc) {
        __syncthreads();
#pragma unroll
        for (int i = 0; i < 4; ++i) {
            int idx = tid + 256 * i;
            int t = idx >> 4;
            int d4 = (idx & 15) * 4;
            float4 v = *(const float4*)(x + (size_t)(tok0 + t) * DIM + kc * 64 + d4);
            xT[d4 + 0][t] = v.x; xT[d4 + 1][t] = v.y;
            xT[d4 + 2][t] = v.z; xT[d4 + 3][t] = v.w;
        }
#pragma unroll
        for (int i = 0; i < 4; ++i) {
            int idx = tid + 256 * i;
            int d = idx >> 4;
            int h4 = (idx & 15) * 4;
            *(float4*)&w1s[d][h4] = *(const float4*)(rw1 + (size_t)(kc * 64 + d) * RH + h4);
        }
        __syncthreads();
#pragma unroll 8
        for (int d = 0; d < 64; ++d) {
            const float4 xa4 = *(const float4*)&xT[d][tt];
            const float4 wv4 = *(const float4*)&w1s[d][hh];
            const float xa[4] = {xa4.x, xa4.y, xa4.z, xa4.w};
            const float wv[4] = {wv4.x, wv4.y, wv4.z, wv4.w};
#pragma unroll
            for (int i = 0; i < 4; ++i)
#pragma unroll
                for (int j = 0; j < 4; ++j)
                    acc[i][j] = fmaf(xa[i], wv[j], acc[i][j]);
        }
    }
    __syncthreads();
    {
        const float4 b4 = *(const float4*)(rb1 + hh);
        const float b[4] = {b4.x, b4.y, b4.z, b4.w};
#pragma unroll
        for (int i = 0; i < 4; ++i) {
            float4 hv;
            hv.x = fmaxf(acc[i][0] + b[0], 0.f);
            hv.y = fmaxf(acc[i][1] + b[1], 0.f);
            hv.z = fmaxf(acc[i][2] + b[2], 0.f);
            hv.w = fmaxf(acc[i][3] + b[3], 0.f);
            *(float4*)&hs[tt + i][hh] = hv;
        }
    }
    __syncthreads();
    {
        int tok = tid >> 2;
        int e0 = (tid & 3) * 4;
        float l[4] = {0.f, 0.f, 0.f, 0.f};
#pragma unroll 8
        for (int k = 0; k < 64; ++k) {
            float hv = hs[tok][k];
            float4 wv = *(const float4*)(rw2 + k * NE + e0);
            l[0] = fmaf(hv, wv.x, l[0]);
            l[1] = fmaf(hv, wv.y, l[1]);
            l[2] = fmaf(hv, wv.z, l[2]);
            l[3] = fmaf(hv, wv.w, l[3]);
        }
        float4 lb = *(const float4*)(rb2 + e0);
        ls[tok][e0 + 0] = l[0] + lb.x;
        ls[tok][e0 + 1] = l[1] + lb.y;
        ls[tok][e0 + 2] = l[2] + lb.z;
        ls[tok][e0 + 3] = l[3] + lb.w;
    }
    __syncthreads();
    if (tid < 64) {
        const int tok = tid;
        const int gt = tok0 + tok;
        float v[16];
        float m = -1e30f;
#pragma unroll
        for (int e = 0; e < 16; ++e) { v[e] = ls[tok][e]; m = fmaxf(m, v[e]); }
        float s = 0.f;
#pragma unroll
        for (int e = 0; e < 16; ++e) { v[e] = expf(v[e] - m); s += v[e]; }
        const float inv = 1.0f / s;
#pragma unroll
        for (int e = 0; e < 16; ++e) v[e] *= inv;
#pragma unroll
        for (int e = 0; e < 16; e += 4) {
            float4 wv = make_float4(v[e], v[e + 1], v[e + 2], v[e + 3]);
            *(float4*)(w_out + (size_t)gt * NE + e) = wv;
        }
        float v1 = -1.f, v2 = -1.f; int i1 = 0, i2 = 0;
#pragma unroll
        for (int e = 0; e < 16; ++e) {
            if (v[e] > v1) { v2 = v1; i2 = i1; v1 = v[e]; i1 = e; }
            else if (v[e] > v2) { v2 = v[e]; i2 = e; }
        }
        const float den = v1 + v2 + 1e-8f;
        atomicAdd(&scnt[i1], 1);
        atomicAdd(&scnt[i2], 1);
        wsi[WS_TOKE + 2 * gt + 0] = i1;
        wsi[WS_TOKE + 2 * gt + 1] = i2;
        wsf[WS_TOKG + 2 * gt + 0] = v1 / den;
        wsf[WS_TOKG + 2 * gt + 1] = v2 / den;
    }
    __syncthreads();
    if (tid < 16 && scnt[tid]) atomicAdd(&wsi[WS_COUNTS + tid], scnt[tid]);
}

// ---------------- Weight prep ----------------
__global__ __launch_bounds__(256) void wprep_kernel(
    const float* __restrict__ ew1, const float* __restrict__ ew2,
    unsigned short* __restrict__ w1t, unsigned short* __restrict__ w2t)
{
    __shared__ float t[64][65];
    int b = blockIdx.x;
    const float* src; unsigned short* dst; int R, C, tr, tc;
    if (b < 128) {
        int e = b >> 3, t8 = b & 7; tr = t8 >> 1; tc = t8 & 1;
        src = ew1 + (size_t)e * DIM * EH; R = DIM; C = EH;
        dst = w1t + (size_t)e * DIM * EH;
    } else {
        int b2 = b - 128; int e = b2 >> 3, t8 = b2 & 7; tr = t8 & 1; tc = t8 >> 1;
        src = ew2 + (size_t)e * EH * DIM; R = EH; C = DIM;
        dst = w2t + (size_t)e * EH * DIM;
    }
    const int R0 = tr * 64, C0 = tc * 64;
    const int tid = threadIdx.x;
#pragma unroll
    for (int q = 0; q < 4; ++q) {
        int r = (tid >> 4) + q * 16, c = (tid & 15) * 4;
        float4 v = *(const float4*)(src + (size_t)(R0 + r) * C + C0 + c);
        t[r][c] = v.x; t[r][c + 1] = v.y; t[r][c + 2] = v.z; t[r][c + 3] = v.w;
    }
    __syncthreads();
#pragma unroll
    for (int q = 0; q < 2; ++q) {
        int rp = (tid >> 3) + q * 32, c0 = (tid & 7) * 8;
        us8 u;
#pragma unroll
        for (int k = 0; k < 8; ++k) u[k] = f2bf(t[c0 + k][rp]);
        *(us8*)(dst + (size_t)(C0 + rp) * R + R0 + c0) = u;
    }
}

// ---------------- Scan ----------------
__global__ __launch_bounds__(64) void scan_kernel(int* __restrict__ wsi)
{
    __shared__ int soff[17], snc[16];
    const int tid = threadIdx.x;
    if (tid == 0) {
        int off = 0, nb = 0;
        soff[0] = 0;
        for (int e = 0; e < NE; ++e) {
            int c = wsi[WS_COUNTS + e];
            wsi[WS_CURSORS + e] = off;
            wsi[WS_OFFSETS + e] = off;
            off += c;
            soff[e + 1] = off;
            snc[e] = nb;
            nb += (c + TB - 1) / TB;
        }
        wsi[WS_OFFSETS + NE] = off;
        wsi[WS_NBLK] = nb;
    }
    __syncthreads();
    for (int e = 0; e < NE; ++e) {
        int nc = (soff[e + 1] - soff[e] + TB - 1) / TB;
        for (int k = tid; k < nc; k += 64)
            wsi[WS_TABLE + snc[e] + k] = (e << 16) | k;
    }
}

// ---------------- Scatter ----------------
__global__ __launch_bounds__(256) void scatter_kernel(int* __restrict__ wsi, float* __restrict__ wsf)
{
    __shared__ int scnt[16], sbase[16];
    const int tid = threadIdx.x;
    const int t = blockIdx.x * 256 + tid;
    if (tid < 16) scnt[tid] = 0;
    __syncthreads();
    const int e0 = wsi[WS_TOKE + 2 * t + 0];
    const int e1 = wsi[WS_TOKE + 2 * t + 1];
    const int l0 = atomicAdd(&scnt[e0], 1);
    const int l1 = atomicAdd(&scnt[e1], 1);
    __syncthreads();
    if (tid < 16) sbase[tid] = scnt[tid] ? atomicAdd(&wsi[WS_CURSORS + tid], scnt[tid]) : 0;
    __syncthreads();
    const int p0 = sbase[e0] + l0;
    const int p1 = sbase[e1] + l1;
    wsi[WS_LIST + p0] = (t << 1);
    wsf[WS_LIST_G + p0] = wsf[WS_TOKG + 2 * t + 0];
    wsi[WS_LIST + p1] = (t << 1) | 1;
    wsf[WS_LIST_G + p1] = wsf[WS_TOKG + 2 * t + 1];
}

// ---------------- Gather ----------------
__global__ __launch_bounds__(256) void gather_kernel(
    const float* __restrict__ x, const int* __restrict__ wsi,
    unsigned short* __restrict__ xg)
{
    const int tid = threadIdx.x;
    const int p = blockIdx.x * 32 + (tid >> 3);
    const int sub = tid & 7;
    const int tok = wsi[WS_LIST + p] >> 1;
    const float* src = x + (size_t)tok * DIM + sub * 32;
    unsigned short* dst = xg + (size_t)p * DIM + sub * 32;
    float4 v[8];
#pragma unroll
    for (int i = 0; i < 8; ++i) v[i] = *(const float4*)(src + i * 4);
#pragma unroll
    for (int i = 0; i < 4; ++i) {
        us8 u;
        u[0] = f2bf(v[2 * i].x);     u[1] = f2bf(v[2 * i].y);
        u[2] = f2bf(v[2 * i].z);     u[3] = f2bf(v[2 * i].w);
        u[4] = f2bf(v[2 * i + 1].x); u[5] = f2bf(v[2 * i + 1].y);
        u[6] = f2bf(v[2 * i + 1].z); u[7] = f2bf(v[2 * i + 1].w);
        *(us8*)(dst + i * 8) = u;
    }
}

// ---------------- Expert: ablation ladder. V=1 stage; V=2 +Wprefetch; V=3 +phase1;
// V=4 +tanh+phase2 (no stores); V=0 full/real. V1..V4 write NOTHING. ----------------
template<int V>
__global__ __launch_bounds__(256, 2) void expert_kernel(
    const unsigned short* __restrict__ xg,
    const float* __restrict__ eb1, const float* __restrict__ eb2,
    const unsigned short* __restrict__ w1t, const unsigned short* __restrict__ w2t,
    const int* __restrict__ wsi, const float* __restrict__ wsf,
    float* __restrict__ y, float* __restrict__ part1)
{
    __shared__ unsigned short smem[16384];
    __shared__ int sl[64];
    __shared__ float sg[64];

    const int nblk = wsi[WS_NBLK];
    const int tid = threadIdx.x;
    const int lane = tid & 63, w = tid >> 6;
    const int l15 = lane & 15;
    const int kq = lane >> 4;
    const int q4 = kq * 4;
    char* lds = (char*)smem;
    f32x4 zero4; zero4[0] = zero4[1] = zero4[2] = zero4[3] = 0.f;

    for (int bi = blockIdx.x; bi < nblk; bi += NPERS) {
        const int ent = wsi[WS_TABLE + bi];
        const int e = ent >> 16;
        const int c = ent & 0xffff;
        const int start = wsi[WS_OFFSETS + e] + c * TB;
        const int cnt = min(TB, wsi[WS_OFFSETS + e + 1] - start);

        __syncthreads();

        // ---- stage loads (all variants) ----
        const char* xrow = (const char*)(xg + (size_t)start * DIM);
        us8 ubuf[8];
#pragma unroll
        for (int i = 0; i < 8; ++i)
            ubuf[i] = *(const us8*)(xrow + (tid + i * 256) * 16);

        // ---- W1 prefetch (V>=2 and V=0) ----
        bf16x8 b1[8][2];
        if constexpr (V != 1) {
            const char* w1e = (const char*)(w1t + (size_t)e * DIM * EH);
#pragma unroll
            for (int ks = 0; ks < 8; ++ks)
#pragma unroll
                for (int nt = 0; nt < 2; ++nt)
                    b1[ks][nt] = *(const bf16x8*)(w1e + (w * 32 + nt * 16 + l15) * 512 + ks * 64 + kq * 16);
        }

        if (tid < 64) {
            sl[tid] = (tid < cnt) ? wsi[WS_LIST + start + tid] : 0;
            sg[tid] = (tid < cnt) ? wsf[WS_LIST_G + start + tid] : 0.f;
        }

#pragma unroll
        for (int i = 0; i < 8; ++i)
            *(us8*)(lds + SWZ9((tid + i * 256) * 16)) = ubuf[i];
        __syncthreads();

        if constexpr (V == 1) continue;

        if constexpr (V == 2) {
            int s = 0;
#pragma unroll
            for (int ks = 0; ks < 8; ++ks)
#pragma unroll
                for (int nt = 0; nt < 2; ++nt)
#pragma unroll
                    for (int j = 0; j < 8; ++j) s += (int)b1[ks][nt][j];
            asm volatile("" :: "v"(s));
            continue;
        }

        // ---- phase 1 (V>=3 and V=0) ----
        f32x4 acc[4][2];
#pragma unroll
        for (int i = 0; i < 4; ++i)
#pragma unroll
            for (int j = 0; j < 2; ++j) acc[i][j] = zero4;

#pragma unroll
        for (int ks = 0; ks < 8; ++ks) {
            bf16x8 a[4];
#pragma unroll
            for (int mt = 0; mt < 4; ++mt)
                a[mt] = *(const bf16x8*)(lds + SWZ9((mt * 16 + l15) * 512 + ks * 64 + kq * 16));
#pragma unroll
            for (int mt = 0; mt < 4; ++mt)
#pragma unroll
                for (int nt = 0; nt < 2; ++nt)
                    acc[mt][nt] = __builtin_amdgcn_mfma_f32_16x16x32_bf16(a[mt], b1[ks][nt], acc[mt][nt], 0, 0, 0);
        }

        if constexpr (V == 3) {
            float s = 0.f;
#pragma unroll
            for (int i = 0; i < 4; ++i)
#pragma unroll
                for (int j = 0; j < 2; ++j)
#pragma unroll
                    for (int r = 0; r < 4; ++r) s += acc[i][j][r];
            asm volatile("" :: "v"(s));
            continue;
        }

        // ---- V==4 or V==0 from here ----
        const char* w2e = (const char*)(w2t + (size_t)e * EH * DIM);
        bf16x8 b2a[4][2];
#pragma unroll
        for (int ks = 0; ks < 4; ++ks)
#pragma unroll
            for (int nt = 0; nt < 2; ++nt)
                b2a[ks][nt] = *(const bf16x8*)(w2e + (w * 64 + nt * 16 + l15) * 256 + ks * 64 + kq * 16);

        __syncthreads();

#pragma unroll
        for (int nt = 0; nt < 2; ++nt) {
            const int h = w * 32 + nt * 16 + l15;
            const float b1v = eb1[e * EH + h];
#pragma unroll
            for (int mt = 0; mt < 4; ++mt)
#pragma unroll
                for (int r = 0; r < 4; ++r) {
                    int tok = mt * 16 + q4 + r;
                    *(unsigned short*)(lds + SWZ8(tok * 256 + h * 2)) = f2bf(fast_tanh(acc[mt][nt][r] + b1v));
                }
        }
        __syncthreads();

        bf16x8 b2b[4][2];
#pragma unroll
        for (int ks = 0; ks < 4; ++ks)
#pragma unroll
            for (int nt = 0; nt < 2; ++nt)
                b2b[ks][nt] = *(const bf16x8*)(w2e + (w * 64 + 32 + nt * 16 + l15) * 256 + ks * 64 + kq * 16);

        // ---- phase 2 half 0 ----
        {
            f32x4 acc2[4][2];
#pragma unroll
            for (int i = 0; i < 4; ++i)
#pragma unroll
                for (int j = 0; j < 2; ++j) acc2[i][j] = zero4;
#pragma unroll
            for (int ks = 0; ks < 4; ++ks) {
                bf16x8 a[4];
#pragma unroll
                for (int mt = 0; mt < 4; ++mt)
                    a[mt] = *(const bf16x8*)(lds + SWZ8((mt * 16 + l15) * 256 + ks * 64 + kq * 16));
#pragma unroll
                for (int mt = 0; mt < 4; ++mt)
#pragma unroll
                    for (int nt = 0; nt < 2; ++nt)
                        acc2[mt][nt] = __builtin_amdgcn_mfma_f32_16x16x32_bf16(a[mt], b2a[ks][nt], acc2[mt][nt], 0, 0, 0);
            }
            float b2v[2];
#pragma unroll
            for (int nt = 0; nt < 2; ++nt)
                b2v[nt] = eb2[e * DIM + w * 64 + nt * 16 + l15];
            if constexpr (V == 4) {
                float s = b2v[0] + b2v[1];
#pragma unroll
                for (int mt = 0; mt < 4; ++mt)
#pragma unroll
                    for (int nt = 0; nt < 2; ++nt)
#pragma unroll
                        for (int r = 0; r < 4; ++r) s += acc2[mt][nt][r];
                asm volatile("" :: "v"(s));
            } else {
#pragma unroll
                for (int mt = 0; mt < 4; ++mt)
#pragma unroll
                    for (int r = 0; r < 4; ++r) {
                        int rl = mt * 16 + q4 + r;
                        if (rl < cnt) {
                            int entry = sl[rl];
                            float g = sg[rl];
                            float* dst = ((entry & 1) ? part1 : y) + (size_t)(entry >> 1) * DIM + w * 64;
#pragma unroll
                            for (int nt = 0; nt < 2; ++nt)
                                dst[nt * 16 + l15] = g * (acc2[mt][nt][r] + b2v[nt]);
                        }
                    }
            }
        }
        // ---- phase 2 half 1 ----
        {
            f32x4 acc2[4][2];
#pragma unroll
            for (int i = 0; i < 4; ++i)
#pragma unroll
                for (int j = 0; j < 2; ++j) acc2[i][j] = zero4;
#pragma unroll
            for (int ks = 0; ks < 4; ++ks) {
                bf16x8 a[4];
#pragma unroll
                for (int mt = 0; mt < 4; ++mt)
                    a[mt] = *(const bf16x8*)(lds + SWZ8((mt * 16 + l15) * 256 + ks * 64 + kq * 16));
#pragma unroll
                for (int mt = 0; mt < 4; ++mt)
#pragma unroll
                    for (int nt = 0; nt < 2; ++nt)
                        acc2[mt][nt] = __builtin_amdgcn_mfma_f32_16x16x32_bf16(a[mt], b2b[ks][nt], acc2[mt][nt], 0, 0, 0);
            }
            float b2v[2];
#pragma unroll
            for (int nt = 0; nt < 2; ++nt)
                b2v[nt] = eb2[e * DIM + w * 64 + 32 + nt * 16 + l15];
            if constexpr (V == 4) {
                float s = b2v[0] + b2v[1];
#pragma unroll
                for (int mt = 0; mt < 4; ++mt)
#pragma unroll
                    for (int nt = 0; nt < 2; ++nt)
#pragma unroll
                        for (int r = 0; r < 4; ++r) s += acc2[mt][nt][r];
                asm volatile("" :: "v"(s));
            } else {
#pragma unroll
                for (int mt = 0; mt < 4; ++mt)
#pragma unroll
                    for (int r = 0; r < 4; ++r) {
                        int rl = mt * 16 + q4 + r;
                        if (rl < cnt) {
                            int entry = sl[rl];
                            float g = sg[rl];
                            float* dst = ((entry & 1) ? part1 : y) + (size_t)(entry >> 1) * DIM + w * 64 + 32;
#pragma unroll
                            for (int nt = 0; nt < 2; ++nt)
                                dst[nt * 16 + l15] = g * (acc2[mt][nt][r] + b2v[nt]);
                        }
                    }
            }
        }
    }
}

// ---------------- Combine ----------------
__global__ __launch_bounds__(256) void combine_kernel(float* __restrict__ y,
                                                      const float* __restrict__ part1)
{
    const size_t i = ((size_t)blockIdx.x * 256 + threadIdx.x) * 4;
    float4 a = *(float4*)(y + i);
    const float4 b = *(const float4*)(part1 + i);
    a.x += b.x; a.y += b.y; a.z += b.z; a.w += b.w;
    *(float4*)(y + i) = a;
}

extern "C" void kernel_launch(void* const* d_in, const int* in_sizes, int n_in,
                              void* d_out, int out_size, void* d_ws, size_t ws_size,
                              hipStream_t stream)
{
    const float* x = (const float*)d_in[0];
    const float* rw1 = (const float*)d_in[1];
    const float* rb1 = (const float*)d_in[2];
    const float* rw2 = (const float*)d_in[3];
    const float* rb2 = (const float*)d_in[4];
    const float* ew1 = (const float*)d_in[5];
    const float* eb1 = (const float*)d_in[6];
    const float* ew2 = (const float*)d_in[7];
    const float* eb2 = (const float*)d_in[8];

    float* y = (float*)d_out;                       // [NT][DIM]
    float* w_out = y + (size_t)NT * DIM;            // [NT][NE]
    int* wsi = (int*)d_ws;
    float* wsf = (float*)d_ws;
    float* part1 = (float*)d_ws;                    // [NT][DIM]
    unsigned short* wsu = (unsigned short*)d_ws;

    hipMemsetAsync(wsi + WS_COUNTS, 0, NE * sizeof(int), stream);

    wprep_kernel<<<256, 256, 0, stream>>>(ew1, ew2, wsu + U_W1T, wsu + U_W2T);
    router_kernel<<<NT / 64, 256, 0, stream>>>(x, rw1, rb1, rw2, rb2, w_out, wsi, wsf);
    scan_kernel<<<1, 64, 0, stream>>>(wsi);
    scatter_kernel<<<NT / 256, 256, 0, stream>>>(wsi, wsf);
    gather_kernel<<<2 * NT / 32, 256, 0, stream>>>(x, wsi, wsu + U_XG);

    // ---- ablation ladder (diagnostic; no output writes) ----
    expert_kernel<1><<<NPERS, 256, 0, stream>>>(wsu + U_XG, eb1, eb2, wsu + U_W1T, wsu + U_W2T, wsi, wsf, y, part1);
    expert_kernel<2><<<NPERS, 256, 0, stream>>>(wsu + U_XG, eb1, eb2, wsu + U_W1T, wsu + U_W2T, wsi, wsf, y, part1);
    expert_kernel<3><<<NPERS, 256, 0, stream>>>(wsu + U_XG, eb1, eb2, wsu + U_W1T, wsu + U_W2T, wsi, wsf, y, part1);
    expert_kernel<4><<<NPERS, 256, 0, stream>>>(wsu + U_XG, eb1, eb2, wsu + U_W1T, wsu + U_W2T, wsi, wsf, y, part1);
    // ---- real ----
    expert_kernel<0><<<NPERS, 256, 0, stream>>>(wsu + U_XG, eb1, eb2, wsu + U_W1T, wsu + U_W2T, wsi, wsf, y, part1);

    combine_kernel<<<NT * DIM / 1024, 256, 0, stream>>>(y, part1);
}

// Round 12
// 121.822 us; speedup vs baseline: 1.6732x; 1.6732x over previous
//
#include <hip/hip_runtime.h>
#include <math.h>

#define NT 32768
#define DIM 256
#define NE 16
#define EH 128
#define RH 64
#define TB 64
#define NPERS 512

// ws layout: float part1[NT*DIM] first, then int/float bookkeeping, then bf16 weights, then xg
#define IB (NT * DIM)
#define WS_COUNTS (IB)
#define WS_OFFSETS (IB + 16)
#define WS_CURSORS (IB + 33)
#define WS_NBLK (IB + 49)
#define WS_TABLE (IB + 64)
#define WS_TOKE (IB + 4096)
#define WS_LIST (WS_TOKE + 2 * NT)
#define WS_TOKG (WS_LIST + 2 * NT)
#define WS_LIST_G (WS_TOKG + 2 * NT)
#define WS_END_I (WS_LIST_G + 2 * NT)
// ushort-unit offsets for bf16 transposed weights + gathered x
#define U_W1T (2 * WS_END_I)
#define U_W2T (U_W1T + NE * DIM * EH)
#define U_XG (U_W2T + NE * DIM * EH)

typedef __attribute__((ext_vector_type(4))) float f32x4;
typedef __attribute__((ext_vector_type(8))) short bf16x8;
typedef __attribute__((ext_vector_type(8))) unsigned short us8;

// XOR swizzles: SWZ9 for 512B-stride tiles, SWZ8 for 256B-stride tiles
#define SWZ9(b) ((b) ^ (((b) >> 5) & 0x70))
#define SWZ8(b) ((b) ^ (((b) >> 4) & 0x70))

__device__ inline unsigned short f2bf(float f) {
    unsigned int bits = __builtin_bit_cast(unsigned int, f);
    bits += 0x7fffu + ((bits >> 16) & 1u);   // RNE
    return (unsigned short)(bits >> 16);
}

__device__ inline float fast_tanh(float v) {
    float cv = fminf(fmaxf(v, -15.f), 15.f);
    float ex = __expf(2.f * cv);
    return (ex - 1.f) / (ex + 1.f);
}

// ---------------- Router ----------------
__global__ __launch_bounds__(256) void router_kernel(
    const float* __restrict__ x,
    const float* __restrict__ rw1, const float* __restrict__ rb1,
    const float* __restrict__ rw2, const float* __restrict__ rb2,
    float* __restrict__ w_out, int* __restrict__ wsi, float* __restrict__ wsf)
{
    __shared__ float xT[64][68];
    __shared__ float w1s[64][64];
    __shared__ float hs[64][68];
    __shared__ float ls[64][20];
    __shared__ int scnt[16];

    const int tid = threadIdx.x;
    const int tok0 = blockIdx.x * 64;
    if (tid < 16) scnt[tid] = 0;

    float acc[4][4];
#pragma unroll
    for (int i = 0; i < 4; ++i)
#pragma unroll
        for (int j = 0; j < 4; ++j) acc[i][j] = 0.f;

    const int tt = (tid & 15) * 4;
    const int hh = (tid >> 4) * 4;

    for (int kc = 0; kc < 4; ++kc) {
        __syncthreads();
#pragma unroll
        for (int i = 0; i < 4; ++i) {
            int idx = tid + 256 * i;
            int t = idx >> 4;
            int d4 = (idx & 15) * 4;
            float4 v = *(const float4*)(x + (size_t)(tok0 + t) * DIM + kc * 64 + d4);
            xT[d4 + 0][t] = v.x; xT[d4 + 1][t] = v.y;
            xT[d4 + 2][t] = v.z; xT[d4 + 3][t] = v.w;
        }
#pragma unroll
        for (int i = 0; i < 4; ++i) {
            int idx = tid + 256 * i;
            int d = idx >> 4;
            int h4 = (idx & 15) * 4;
            *(float4*)&w1s[d][h4] = *(const float4*)(rw1 + (size_t)(kc * 64 + d) * RH + h4);
        }
        __syncthreads();
#pragma unroll 8
        for (int d = 0; d < 64; ++d) {
            const float4 xa4 = *(const float4*)&xT[d][tt];
            const float4 wv4 = *(const float4*)&w1s[d][hh];
            const float xa[4] = {xa4.x, xa4.y, xa4.z, xa4.w};
            const float wv[4] = {wv4.x, wv4.y, wv4.z, wv4.w};
#pragma unroll
            for (int i = 0; i < 4; ++i)
#pragma unroll
                for (int j = 0; j < 4; ++j)
                    acc[i][j] = fmaf(xa[i], wv[j], acc[i][j]);
        }
    }
    __syncthreads();
    {
        const float4 b4 = *(const float4*)(rb1 + hh);
        const float b[4] = {b4.x, b4.y, b4.z, b4.w};
#pragma unroll
        for (int i = 0; i < 4; ++i) {
            float4 hv;
            hv.x = fmaxf(acc[i][0] + b[0], 0.f);
            hv.y = fmaxf(acc[i][1] + b[1], 0.f);
            hv.z = fmaxf(acc[i][2] + b[2], 0.f);
            hv.w = fmaxf(acc[i][3] + b[3], 0.f);
            *(float4*)&hs[tt + i][hh] = hv;
        }
    }
    __syncthreads();
    {
        int tok = tid >> 2;
        int e0 = (tid & 3) * 4;
        float l[4] = {0.f, 0.f, 0.f, 0.f};
#pragma unroll 8
        for (int k = 0; k < 64; ++k) {
            float hv = hs[tok][k];
            float4 wv = *(const float4*)(rw2 + k * NE + e0);
            l[0] = fmaf(hv, wv.x, l[0]);
            l[1] = fmaf(hv, wv.y, l[1]);
            l[2] = fmaf(hv, wv.z, l[2]);
            l[3] = fmaf(hv, wv.w, l[3]);
        }
        float4 lb = *(const float4*)(rb2 + e0);
        ls[tok][e0 + 0] = l[0] + lb.x;
        ls[tok][e0 + 1] = l[1] + lb.y;
        ls[tok][e0 + 2] = l[2] + lb.z;
        ls[tok][e0 + 3] = l[3] + lb.w;
    }
    __syncthreads();
    if (tid < 64) {
        const int tok = tid;
        const int gt = tok0 + tok;
        float v[16];
        float m = -1e30f;
#pragma unroll
        for (int e = 0; e < 16; ++e) { v[e] = ls[tok][e]; m = fmaxf(m, v[e]); }
        float s = 0.f;
#pragma unroll
        for (int e = 0; e < 16; ++e) { v[e] = expf(v[e] - m); s += v[e]; }
        const float inv = 1.0f / s;
#pragma unroll
        for (int e = 0; e < 16; ++e) v[e] *= inv;
#pragma unroll
        for (int e = 0; e < 16; e += 4) {
            float4 wv = make_float4(v[e], v[e + 1], v[e + 2], v[e + 3]);
            *(float4*)(w_out + (size_t)gt * NE + e) = wv;
        }
        float v1 = -1.f, v2 = -1.f; int i1 = 0, i2 = 0;
#pragma unroll
        for (int e = 0; e < 16; ++e) {
            if (v[e] > v1) { v2 = v1; i2 = i1; v1 = v[e]; i1 = e; }
            else if (v[e] > v2) { v2 = v[e]; i2 = e; }
        }
        const float den = v1 + v2 + 1e-8f;
        atomicAdd(&scnt[i1], 1);
        atomicAdd(&scnt[i2], 1);
        wsi[WS_TOKE + 2 * gt + 0] = i1;
        wsi[WS_TOKE + 2 * gt + 1] = i2;
        wsf[WS_TOKG + 2 * gt + 0] = v1 / den;
        wsf[WS_TOKG + 2 * gt + 1] = v2 / den;
    }
    __syncthreads();
    if (tid < 16 && scnt[tid]) atomicAdd(&wsi[WS_COUNTS + tid], scnt[tid]);
}

// ---------------- Weight prep ----------------
__global__ __launch_bounds__(256) void wprep_kernel(
    const float* __restrict__ ew1, const float* __restrict__ ew2,
    unsigned short* __restrict__ w1t, unsigned short* __restrict__ w2t)
{
    __shared__ float t[64][65];
    int b = blockIdx.x;
    const float* src; unsigned short* dst; int R, C, tr, tc;
    if (b < 128) {
        int e = b >> 3, t8 = b & 7; tr = t8 >> 1; tc = t8 & 1;
        src = ew1 + (size_t)e * DIM * EH; R = DIM; C = EH;
        dst = w1t + (size_t)e * DIM * EH;
    } else {
        int b2 = b - 128; int e = b2 >> 3, t8 = b2 & 7; tr = t8 & 1; tc = t8 >> 1;
        src = ew2 + (size_t)e * EH * DIM; R = EH; C = DIM;
        dst = w2t + (size_t)e * EH * DIM;
    }
    const int R0 = tr * 64, C0 = tc * 64;
    const int tid = threadIdx.x;
#pragma unroll
    for (int q = 0; q < 4; ++q) {
        int r = (tid >> 4) + q * 16, c = (tid & 15) * 4;
        float4 v = *(const float4*)(src + (size_t)(R0 + r) * C + C0 + c);
        t[r][c] = v.x; t[r][c + 1] = v.y; t[r][c + 2] = v.z; t[r][c + 3] = v.w;
    }
    __syncthreads();
#pragma unroll
    for (int q = 0; q < 2; ++q) {
        int rp = (tid >> 3) + q * 32, c0 = (tid & 7) * 8;
        us8 u;
#pragma unroll
        for (int k = 0; k < 8; ++k) u[k] = f2bf(t[c0 + k][rp]);
        *(us8*)(dst + (size_t)(C0 + rp) * R + R0 + c0) = u;
    }
}

// ---------------- Scan ----------------
__global__ __launch_bounds__(64) void scan_kernel(int* __restrict__ wsi)
{
    __shared__ int soff[17], snc[16];
    const int tid = threadIdx.x;
    if (tid == 0) {
        int off = 0, nb = 0;
        soff[0] = 0;
        for (int e = 0; e < NE; ++e) {
            int c = wsi[WS_COUNTS + e];
            wsi[WS_CURSORS + e] = off;
            wsi[WS_OFFSETS + e] = off;
            off += c;
            soff[e + 1] = off;
            snc[e] = nb;
            nb += (c + TB - 1) / TB;
        }
        wsi[WS_OFFSETS + NE] = off;
        wsi[WS_NBLK] = nb;
    }
    __syncthreads();
    for (int e = 0; e < NE; ++e) {
        int nc = (soff[e + 1] - soff[e] + TB - 1) / TB;
        for (int k = tid; k < nc; k += 64)
            wsi[WS_TABLE + snc[e] + k] = (e << 16) | k;
    }
}

// ---------------- Scatter ----------------
__global__ __launch_bounds__(256) void scatter_kernel(int* __restrict__ wsi, float* __restrict__ wsf)
{
    __shared__ int scnt[16], sbase[16];
    const int tid = threadIdx.x;
    const int t = blockIdx.x * 256 + tid;
    if (tid < 16) scnt[tid] = 0;
    __syncthreads();
    const int e0 = wsi[WS_TOKE + 2 * t + 0];
    const int e1 = wsi[WS_TOKE + 2 * t + 1];
    const int l0 = atomicAdd(&scnt[e0], 1);
    const int l1 = atomicAdd(&scnt[e1], 1);
    __syncthreads();
    if (tid < 16) sbase[tid] = scnt[tid] ? atomicAdd(&wsi[WS_CURSORS + tid], scnt[tid]) : 0;
    __syncthreads();
    const int p0 = sbase[e0] + l0;
    const int p1 = sbase[e1] + l1;
    wsi[WS_LIST + p0] = (t << 1);
    wsf[WS_LIST_G + p0] = wsf[WS_TOKG + 2 * t + 0];
    wsi[WS_LIST + p1] = (t << 1) | 1;
    wsf[WS_LIST_G + p1] = wsf[WS_TOKG + 2 * t + 1];
}

// ---------------- Gather ----------------
__global__ __launch_bounds__(256) void gather_kernel(
    const float* __restrict__ x, const int* __restrict__ wsi,
    unsigned short* __restrict__ xg)
{
    const int tid = threadIdx.x;
    const int p = blockIdx.x * 32 + (tid >> 3);
    const int sub = tid & 7;
    const int tok = wsi[WS_LIST + p] >> 1;
    const float* src = x + (size_t)tok * DIM + sub * 32;
    unsigned short* dst = xg + (size_t)p * DIM + sub * 32;
    float4 v[8];
#pragma unroll
    for (int i = 0; i < 8; ++i) v[i] = *(const float4*)(src + i * 4);
#pragma unroll
    for (int i = 0; i < 4; ++i) {
        us8 u;
        u[0] = f2bf(v[2 * i].x);     u[1] = f2bf(v[2 * i].y);
        u[2] = f2bf(v[2 * i].z);     u[3] = f2bf(v[2 * i].w);
        u[4] = f2bf(v[2 * i + 1].x); u[5] = f2bf(v[2 * i + 1].y);
        u[6] = f2bf(v[2 * i + 1].z); u[7] = f2bf(v[2 * i + 1].w);
        *(us8*)(dst + i * 8) = u;
    }
}

// ---------------- Expert: persistent, LDS-transposed vectorized epilogue ----------------
__global__ __launch_bounds__(256, 2) void expert_kernel(
    const unsigned short* __restrict__ xg,
    const float* __restrict__ eb1, const float* __restrict__ eb2,
    const unsigned short* __restrict__ w1t, const unsigned short* __restrict__ w2t,
    const int* __restrict__ wsi, const float* __restrict__ wsf,
    float* __restrict__ y, float* __restrict__ part1)
{
    __shared__ unsigned short smem[16384];   // 32 KB: Xs[64][256] bf16, later hT[64][128] bf16
    __shared__ float obuf[64 * 132];         // 33 KB f32 output staging, pad 4
    __shared__ int sl[64];
    __shared__ float sg[64];

    const int nblk = wsi[WS_NBLK];
    const int tid = threadIdx.x;
    const int lane = tid & 63, w = tid >> 6;
    const int l15 = lane & 15;
    const int kq = lane >> 4;
    const int q4 = kq * 4;
    const int l7 = tid & 7;
    char* lds = (char*)smem;
    f32x4 zero4; zero4[0] = zero4[1] = zero4[2] = zero4[3] = 0.f;

    for (int bi = blockIdx.x; bi < nblk; bi += NPERS) {
        const int ent = wsi[WS_TABLE + bi];
        const int e = ent >> 16;
        const int c = ent & 0xffff;
        const int start = wsi[WS_OFFSETS + e] + c * TB;
        const int cnt = min(TB, wsi[WS_OFFSETS + e + 1] - start);

        __syncthreads();   // previous iteration's LDS/obuf reads complete

        // ---- sequential xg stage loads ----
        const char* xrow = (const char*)(xg + (size_t)start * DIM);
        us8 ubuf[8];
#pragma unroll
        for (int i = 0; i < 8; ++i)
            ubuf[i] = *(const us8*)(xrow + (tid + i * 256) * 16);

        // ---- W1 register prefetch ----
        const char* w1e = (const char*)(w1t + (size_t)e * DIM * EH);
        bf16x8 b1[8][2];
#pragma unroll
        for (int ks = 0; ks < 8; ++ks)
#pragma unroll
            for (int nt = 0; nt < 2; ++nt)
                b1[ks][nt] = *(const bf16x8*)(w1e + (w * 32 + nt * 16 + l15) * 512 + ks * 64 + kq * 16);

        if (tid < 64) {
            sl[tid] = (tid < cnt) ? wsi[WS_LIST + start + tid] : 0;
            sg[tid] = (tid < cnt) ? wsf[WS_LIST_G + start + tid] : 0.f;
        }

#pragma unroll
        for (int i = 0; i < 8; ++i)
            *(us8*)(lds + SWZ9((tid + i * 256) * 16)) = ubuf[i];
        __syncthreads();

        // ---- phase 1: C1[64 tok][32 h per wave] ----
        f32x4 acc[4][2];
#pragma unroll
        for (int i = 0; i < 4; ++i)
#pragma unroll
            for (int j = 0; j < 2; ++j) acc[i][j] = zero4;

#pragma unroll
        for (int ks = 0; ks < 8; ++ks) {
            bf16x8 a[4];
#pragma unroll
            for (int mt = 0; mt < 4; ++mt)
                a[mt] = *(const bf16x8*)(lds + SWZ9((mt * 16 + l15) * 512 + ks * 64 + kq * 16));
#pragma unroll
            for (int mt = 0; mt < 4; ++mt)
#pragma unroll
                for (int nt = 0; nt < 2; ++nt)
                    acc[mt][nt] = __builtin_amdgcn_mfma_f32_16x16x32_bf16(a[mt], b1[ks][nt], acc[mt][nt], 0, 0, 0);
        }

        // ---- prefetch phase-2 W2 fragments (both halves; hides under tanh) ----
        const char* w2e = (const char*)(w2t + (size_t)e * EH * DIM);
        bf16x8 b2a[4][2];
#pragma unroll
        for (int ks = 0; ks < 4; ++ks)
#pragma unroll
            for (int nt = 0; nt < 2; ++nt)
                b2a[ks][nt] = *(const bf16x8*)(w2e + (w * 64 + nt * 16 + l15) * 256 + ks * 64 + kq * 16);

        __syncthreads();   // phase-1 LDS reads complete

        // ---- h = tanh(C1 + b1) -> hT SWZ8 ----
#pragma unroll
        for (int nt = 0; nt < 2; ++nt) {
            const int h = w * 32 + nt * 16 + l15;
            const float b1v = eb1[e * EH + h];
#pragma unroll
            for (int mt = 0; mt < 4; ++mt)
#pragma unroll
                for (int r = 0; r < 4; ++r) {
                    int tok = mt * 16 + q4 + r;
                    *(unsigned short*)(lds + SWZ8(tok * 256 + h * 2)) = f2bf(fast_tanh(acc[mt][nt][r] + b1v));
                }
        }
        __syncthreads();

        bf16x8 b2b[4][2];
#pragma unroll
        for (int ks = 0; ks < 4; ++ks)
#pragma unroll
            for (int nt = 0; nt < 2; ++nt)
                b2b[ks][nt] = *(const bf16x8*)(w2e + (w * 64 + 32 + nt * 16 + l15) * 256 + ks * 64 + kq * 16);

        // ---- phase 2 half 0: MFMA -> obuf fragments (bias added, gate deferred) ----
        {
            f32x4 acc2[4][2];
#pragma unroll
            for (int i = 0; i < 4; ++i)
#pragma unroll
                for (int j = 0; j < 2; ++j) acc2[i][j] = zero4;
#pragma unroll
            for (int ks = 0; ks < 4; ++ks) {
                bf16x8 a[4];
#pragma unroll
                for (int mt = 0; mt < 4; ++mt)
                    a[mt] = *(const bf16x8*)(lds + SWZ8((mt * 16 + l15) * 256 + ks * 64 + kq * 16));
#pragma unroll
                for (int mt = 0; mt < 4; ++mt)
#pragma unroll
                    for (int nt = 0; nt < 2; ++nt)
                        acc2[mt][nt] = __builtin_amdgcn_mfma_f32_16x16x32_bf16(a[mt], b2a[ks][nt], acc2[mt][nt], 0, 0, 0);
            }
            float b2v[2];
#pragma unroll
            for (int nt = 0; nt < 2; ++nt)
                b2v[nt] = eb2[e * DIM + w * 64 + nt * 16 + l15];
#pragma unroll
            for (int mt = 0; mt < 4; ++mt)
#pragma unroll
                for (int nt = 0; nt < 2; ++nt)
#pragma unroll
                    for (int r = 0; r < 4; ++r)
                        obuf[(mt * 16 + q4 + r) * 132 + w * 32 + nt * 16 + l15] = acc2[mt][nt][r] + b2v[nt];
        }
        __syncthreads();   // half-0 fragments staged

        // ---- half-0 vectorized scattered stores (128B segments, fire-and-forget) ----
#pragma unroll
        for (int round = 0; round < 8; ++round) {
            int slot = round * 32 + (tid >> 3);
            int row = slot >> 2, win = slot & 3;
            if (row < cnt) {
                float4 v = *(float4*)&obuf[row * 132 + win * 32 + l7 * 4];
                int entry = sl[row];
                float g = sg[row];
                float* dst = ((entry & 1) ? part1 : y) + (size_t)(entry >> 1) * DIM + win * 64 + l7 * 4;
                float4 o = make_float4(g * v.x, g * v.y, g * v.z, g * v.w);
                *(float4*)dst = o;
            }
        }

        // ---- phase 2 half 1: MFMA (hT reads; overlaps half-0 store drain) ----
        {
            f32x4 acc2[4][2];
#pragma unroll
            for (int i = 0; i < 4; ++i)
#pragma unroll
                for (int j = 0; j < 2; ++j) acc2[i][j] = zero4;
#pragma unroll
            for (int ks = 0; ks < 4; ++ks) {
                bf16x8 a[4];
#pragma unroll
                for (int mt = 0; mt < 4; ++mt)
                    a[mt] = *(const bf16x8*)(lds + SWZ8((mt * 16 + l15) * 256 + ks * 64 + kq * 16));
#pragma unroll
                for (int mt = 0; mt < 4; ++mt)
#pragma unroll
                    for (int nt = 0; nt < 2; ++nt)
                        acc2[mt][nt] = __builtin_amdgcn_mfma_f32_16x16x32_bf16(a[mt], b2b[ks][nt], acc2[mt][nt], 0, 0, 0);
            }
            float b2v[2];
#pragma unroll
            for (int nt = 0; nt < 2; ++nt)
                b2v[nt] = eb2[e * DIM + w * 64 + 32 + nt * 16 + l15];
            __syncthreads();   // half-0 obuf reads complete everywhere
#pragma unroll
            for (int mt = 0; mt < 4; ++mt)
#pragma unroll
                for (int nt = 0; nt < 2; ++nt)
#pragma unroll
                    for (int r = 0; r < 4; ++r)
                        obuf[(mt * 16 + q4 + r) * 132 + w * 32 + nt * 16 + l15] = acc2[mt][nt][r] + b2v[nt];
        }
        __syncthreads();   // half-1 fragments staged

        // ---- half-1 vectorized scattered stores ----
#pragma unroll
        for (int round = 0; round < 8; ++round) {
            int slot = round * 32 + (tid >> 3);
            int row = slot >> 2, win = slot & 3;
            if (row < cnt) {
                float4 v = *(float4*)&obuf[row * 132 + win * 32 + l7 * 4];
                int entry = sl[row];
                float g = sg[row];
                float* dst = ((entry & 1) ? part1 : y) + (size_t)(entry >> 1) * DIM + win * 64 + 32 + l7 * 4;
                float4 o = make_float4(g * v.x, g * v.y, g * v.z, g * v.w);
                *(float4*)dst = o;
            }
        }
    }
}

// ---------------- Combine ----------------
__global__ __launch_bounds__(256) void combine_kernel(float* __restrict__ y,
                                                      const float* __restrict__ part1)
{
    const size_t i = ((size_t)blockIdx.x * 256 + threadIdx.x) * 4;
    float4 a = *(float4*)(y + i);
    const float4 b = *(const float4*)(part1 + i);
    a.x += b.x; a.y += b.y; a.z += b.z; a.w += b.w;
    *(float4*)(y + i) = a;
}

extern "C" void kernel_launch(void* const* d_in, const int* in_sizes, int n_in,
                              void* d_out, int out_size, void* d_ws, size_t ws_size,
                              hipStream_t stream)
{
    const float* x = (const float*)d_in[0];
    const float* rw1 = (const float*)d_in[1];
    const float* rb1 = (const float*)d_in[2];
    const float* rw2 = (const float*)d_in[3];
    const float* rb2 = (const float*)d_in[4];
    const float* ew1 = (const float*)d_in[5];
    const float* eb1 = (const float*)d_in[6];
    const float* ew2 = (const float*)d_in[7];
    const float* eb2 = (const float*)d_in[8];

    float* y = (float*)d_out;                       // [NT][DIM]
    float* w_out = y + (size_t)NT * DIM;            // [NT][NE]
    int* wsi = (int*)d_ws;
    float* wsf = (float*)d_ws;
    float* part1 = (float*)d_ws;                    // [NT][DIM]
    unsigned short* wsu = (unsigned short*)d_ws;

    hipMemsetAsync(wsi + WS_COUNTS, 0, NE * sizeof(int), stream);

    wprep_kernel<<<256, 256, 0, stream>>>(ew1, ew2, wsu + U_W1T, wsu + U_W2T);
    router_kernel<<<NT / 64, 256, 0, stream>>>(x, rw1, rb1, rw2, rb2, w_out, wsi, wsf);
    scan_kernel<<<1, 64, 0, stream>>>(wsi);
    scatter_kernel<<<NT / 256, 256, 0, stream>>>(wsi, wsf);
    gather_kernel<<<2 * NT / 32, 256, 0, stream>>>(x, wsi, wsu + U_XG);
    expert_kernel<<<NPERS, 256, 0, stream>>>(wsu + U_XG, eb1, eb2,
                                             wsu + U_W1T, wsu + U_W2T,
                                             wsi, wsf, y, part1);
    combine_kernel<<<NT * DIM / 1024, 256, 0, stream>>>(y, part1);
}

// Round 13
// 121.330 us; speedup vs baseline: 1.6800x; 1.0041x over previous
//
#include <hip/hip_runtime.h>
#include <math.h>

#define NT 32768
#define DIM 256
#define NE 16
#define EH 128
#define RH 64
#define TB 64
#define NPERS 512

// ws layout: bf16 out_lin[2NT][256] first (= old part1 footprint), then bookkeeping,
// then bf16 weights, then xg
#define IB (NT * DIM)
#define WS_COUNTS (IB)
#define WS_OFFSETS (IB + 16)
#define WS_CURSORS (IB + 33)
#define WS_NBLK (IB + 49)
#define WS_TABLE (IB + 64)
#define WS_TOKE (IB + 4096)
#define WS_LIST (WS_TOKE + 2 * NT)
#define WS_TOKG (WS_LIST + 2 * NT)
#define WS_INV (WS_TOKG + 2 * NT)
#define WS_END_I (WS_INV + 2 * NT)
// ushort-unit offsets
#define U_OUT 0
#define U_W1T (2 * WS_END_I)
#define U_W2T (U_W1T + NE * DIM * EH)
#define U_XG (U_W2T + NE * DIM * EH)

typedef __attribute__((ext_vector_type(4))) float f32x4;
typedef __attribute__((ext_vector_type(8))) short bf16x8;
typedef __attribute__((ext_vector_type(8))) unsigned short us8;

// XOR swizzles: SWZ9 for 512B-stride tiles, SWZ8 for 256B-stride tiles
#define SWZ9(b) ((b) ^ (((b) >> 5) & 0x70))
#define SWZ8(b) ((b) ^ (((b) >> 4) & 0x70))

__device__ inline unsigned short f2bf(float f) {
    unsigned int bits = __builtin_bit_cast(unsigned int, f);
    bits += 0x7fffu + ((bits >> 16) & 1u);   // RNE
    return (unsigned short)(bits >> 16);
}
__device__ inline float bf2f(unsigned short u) {
    unsigned int v = ((unsigned int)u) << 16;
    return __builtin_bit_cast(float, v);
}
__device__ inline float fast_tanh(float v) {
    float cv = fminf(fmaxf(v, -15.f), 15.f);
    float ex = __expf(2.f * cv);
    return (ex - 1.f) / (ex + 1.f);
}

// ---------------- Router ----------------
__global__ __launch_bounds__(256) void router_kernel(
    const float* __restrict__ x,
    const float* __restrict__ rw1, const float* __restrict__ rb1,
    const float* __restrict__ rw2, const float* __restrict__ rb2,
    float* __restrict__ w_out, int* __restrict__ wsi, float* __restrict__ wsf)
{
    __shared__ float xT[64][68];
    __shared__ float w1s[64][64];
    __shared__ float hs[64][68];
    __shared__ float ls[64][20];
    __shared__ int scnt[16];

    const int tid = threadIdx.x;
    const int tok0 = blockIdx.x * 64;
    if (tid < 16) scnt[tid] = 0;

    float acc[4][4];
#pragma unroll
    for (int i = 0; i < 4; ++i)
#pragma unroll
        for (int j = 0; j < 4; ++j) acc[i][j] = 0.f;

    const int tt = (tid & 15) * 4;
    const int hh = (tid >> 4) * 4;

    for (int kc = 0; kc < 4; ++kc) {
        __syncthreads();
#pragma unroll
        for (int i = 0; i < 4; ++i) {
            int idx = tid + 256 * i;
            int t = idx >> 4;
            int d4 = (idx & 15) * 4;
            float4 v = *(const float4*)(x + (size_t)(tok0 + t) * DIM + kc * 64 + d4);
            xT[d4 + 0][t] = v.x; xT[d4 + 1][t] = v.y;
            xT[d4 + 2][t] = v.z; xT[d4 + 3][t] = v.w;
        }
#pragma unroll
        for (int i = 0; i < 4; ++i) {
            int idx = tid + 256 * i;
            int d = idx >> 4;
            int h4 = (idx & 15) * 4;
            *(float4*)&w1s[d][h4] = *(const float4*)(rw1 + (size_t)(kc * 64 + d) * RH + h4);
        }
        __syncthreads();
#pragma unroll 8
        for (int d = 0; d < 64; ++d) {
            const float4 xa4 = *(const float4*)&xT[d][tt];
            const float4 wv4 = *(const float4*)&w1s[d][hh];
            const float xa[4] = {xa4.x, xa4.y, xa4.z, xa4.w};
            const float wv[4] = {wv4.x, wv4.y, wv4.z, wv4.w};
#pragma unroll
            for (int i = 0; i < 4; ++i)
#pragma unroll
                for (int j = 0; j < 4; ++j)
                    acc[i][j] = fmaf(xa[i], wv[j], acc[i][j]);
        }
    }
    __syncthreads();
    {
        const float4 b4 = *(const float4*)(rb1 + hh);
        const float b[4] = {b4.x, b4.y, b4.z, b4.w};
#pragma unroll
        for (int i = 0; i < 4; ++i) {
            float4 hv;
            hv.x = fmaxf(acc[i][0] + b[0], 0.f);
            hv.y = fmaxf(acc[i][1] + b[1], 0.f);
            hv.z = fmaxf(acc[i][2] + b[2], 0.f);
            hv.w = fmaxf(acc[i][3] + b[3], 0.f);
            *(float4*)&hs[tt + i][hh] = hv;
        }
    }
    __syncthreads();
    {
        int tok = tid >> 2;
        int e0 = (tid & 3) * 4;
        float l[4] = {0.f, 0.f, 0.f, 0.f};
#pragma unroll 8
        for (int k = 0; k < 64; ++k) {
            float hv = hs[tok][k];
            float4 wv = *(const float4*)(rw2 + k * NE + e0);
            l[0] = fmaf(hv, wv.x, l[0]);
            l[1] = fmaf(hv, wv.y, l[1]);
            l[2] = fmaf(hv, wv.z, l[2]);
            l[3] = fmaf(hv, wv.w, l[3]);
        }
        float4 lb = *(const float4*)(rb2 + e0);
        ls[tok][e0 + 0] = l[0] + lb.x;
        ls[tok][e0 + 1] = l[1] + lb.y;
        ls[tok][e0 + 2] = l[2] + lb.z;
        ls[tok][e0 + 3] = l[3] + lb.w;
    }
    __syncthreads();
    if (tid < 64) {
        const int tok = tid;
        const int gt = tok0 + tok;
        float v[16];
        float m = -1e30f;
#pragma unroll
        for (int e = 0; e < 16; ++e) { v[e] = ls[tok][e]; m = fmaxf(m, v[e]); }
        float s = 0.f;
#pragma unroll
        for (int e = 0; e < 16; ++e) { v[e] = expf(v[e] - m); s += v[e]; }
        const float inv = 1.0f / s;
#pragma unroll
        for (int e = 0; e < 16; ++e) v[e] *= inv;
#pragma unroll
        for (int e = 0; e < 16; e += 4) {
            float4 wv = make_float4(v[e], v[e + 1], v[e + 2], v[e + 3]);
            *(float4*)(w_out + (size_t)gt * NE + e) = wv;
        }
        float v1 = -1.f, v2 = -1.f; int i1 = 0, i2 = 0;
#pragma unroll
        for (int e = 0; e < 16; ++e) {
            if (v[e] > v1) { v2 = v1; i2 = i1; v1 = v[e]; i1 = e; }
            else if (v[e] > v2) { v2 = v[e]; i2 = e; }
        }
        const float den = v1 + v2 + 1e-8f;
        atomicAdd(&scnt[i1], 1);
        atomicAdd(&scnt[i2], 1);
        wsi[WS_TOKE + 2 * gt + 0] = i1;
        wsi[WS_TOKE + 2 * gt + 1] = i2;
        wsf[WS_TOKG + 2 * gt + 0] = v1 / den;
        wsf[WS_TOKG + 2 * gt + 1] = v2 / den;
    }
    __syncthreads();
    if (tid < 16 && scnt[tid]) atomicAdd(&wsi[WS_COUNTS + tid], scnt[tid]);
}

// ---------------- Weight prep ----------------
__global__ __launch_bounds__(256) void wprep_kernel(
    const float* __restrict__ ew1, const float* __restrict__ ew2,
    unsigned short* __restrict__ w1t, unsigned short* __restrict__ w2t)
{
    __shared__ float t[64][65];
    int b = blockIdx.x;
    const float* src; unsigned short* dst; int R, C, tr, tc;
    if (b < 128) {
        int e = b >> 3, t8 = b & 7; tr = t8 >> 1; tc = t8 & 1;
        src = ew1 + (size_t)e * DIM * EH; R = DIM; C = EH;
        dst = w1t + (size_t)e * DIM * EH;
    } else {
        int b2 = b - 128; int e = b2 >> 3, t8 = b2 & 7; tr = t8 & 1; tc = t8 >> 1;
        src = ew2 + (size_t)e * EH * DIM; R = EH; C = DIM;
        dst = w2t + (size_t)e * EH * DIM;
    }
    const int R0 = tr * 64, C0 = tc * 64;
    const int tid = threadIdx.x;
#pragma unroll
    for (int q = 0; q < 4; ++q) {
        int r = (tid >> 4) + q * 16, c = (tid & 15) * 4;
        float4 v = *(const float4*)(src + (size_t)(R0 + r) * C + C0 + c);
        t[r][c] = v.x; t[r][c + 1] = v.y; t[r][c + 2] = v.z; t[r][c + 3] = v.w;
    }
    __syncthreads();
#pragma unroll
    for (int q = 0; q < 2; ++q) {
        int rp = (tid >> 3) + q * 32, c0 = (tid & 7) * 8;
        us8 u;
#pragma unroll
        for (int k = 0; k < 8; ++k) u[k] = f2bf(t[c0 + k][rp]);
        *(us8*)(dst + (size_t)(C0 + rp) * R + R0 + c0) = u;
    }
}

// ---------------- Scan ----------------
__global__ __launch_bounds__(64) void scan_kernel(int* __restrict__ wsi)
{
    __shared__ int soff[17], snc[16];
    const int tid = threadIdx.x;
    if (tid == 0) {
        int off = 0, nb = 0;
        soff[0] = 0;
        for (int e = 0; e < NE; ++e) {
            int c = wsi[WS_COUNTS + e];
            wsi[WS_CURSORS + e] = off;
            wsi[WS_OFFSETS + e] = off;
            off += c;
            soff[e + 1] = off;
            snc[e] = nb;
            nb += (c + TB - 1) / TB;
        }
        wsi[WS_OFFSETS + NE] = off;
        wsi[WS_NBLK] = nb;
    }
    __syncthreads();
    for (int e = 0; e < NE; ++e) {
        int nc = (soff[e + 1] - soff[e] + TB - 1) / TB;
        for (int k = tid; k < nc; k += 64)
            wsi[WS_TABLE + snc[e] + k] = (e << 16) | k;
    }
}

// ---------------- Scatter: list + inverse map ----------------
__global__ __launch_bounds__(256) void scatter_kernel(int* __restrict__ wsi)
{
    __shared__ int scnt[16], sbase[16];
    const int tid = threadIdx.x;
    const int t = blockIdx.x * 256 + tid;
    if (tid < 16) scnt[tid] = 0;
    __syncthreads();
    const int e0 = wsi[WS_TOKE + 2 * t + 0];
    const int e1 = wsi[WS_TOKE + 2 * t + 1];
    const int l0 = atomicAdd(&scnt[e0], 1);
    const int l1 = atomicAdd(&scnt[e1], 1);
    __syncthreads();
    if (tid < 16) sbase[tid] = scnt[tid] ? atomicAdd(&wsi[WS_CURSORS + tid], scnt[tid]) : 0;
    __syncthreads();
    const int p0 = sbase[e0] + l0;
    const int p1 = sbase[e1] + l1;
    wsi[WS_LIST + p0] = t;
    wsi[WS_LIST + p1] = t;
    wsi[WS_INV + 2 * t + 0] = p0;
    wsi[WS_INV + 2 * t + 1] = p1;
}

// ---------------- Gather: xg[p][256] = bf16(x[list[p]][256]) ----------------
__global__ __launch_bounds__(256) void gather_kernel(
    const float* __restrict__ x, const int* __restrict__ wsi,
    unsigned short* __restrict__ xg)
{
    const int tid = threadIdx.x;
    const int p = blockIdx.x * 32 + (tid >> 3);
    const int sub = tid & 7;
    const int tok = wsi[WS_LIST + p];
    const float* src = x + (size_t)tok * DIM + sub * 32;
    unsigned short* dst = xg + (size_t)p * DIM + sub * 32;
    float4 v[8];
#pragma unroll
    for (int i = 0; i < 8; ++i) v[i] = *(const float4*)(src + i * 4);
#pragma unroll
    for (int i = 0; i < 4; ++i) {
        us8 u;
        u[0] = f2bf(v[2 * i].x);     u[1] = f2bf(v[2 * i].y);
        u[2] = f2bf(v[2 * i].z);     u[3] = f2bf(v[2 * i].w);
        u[4] = f2bf(v[2 * i + 1].x); u[5] = f2bf(v[2 * i + 1].y);
        u[6] = f2bf(v[2 * i + 1].z); u[7] = f2bf(v[2 * i + 1].w);
        *(us8*)(dst + i * 8) = u;
    }
}

// ---------------- Expert: persistent, LINEAR bf16 output in list order ----------------
__global__ __launch_bounds__(256, 2) void expert_kernel(
    const unsigned short* __restrict__ xg,
    const float* __restrict__ eb1, const float* __restrict__ eb2,
    const unsigned short* __restrict__ w1t, const unsigned short* __restrict__ w2t,
    const int* __restrict__ wsi,
    unsigned short* __restrict__ out_lin)
{
    __shared__ unsigned short smem[16384];        // 32 KB: Xs[64][256] bf16, later hT[64][128] bf16
    __shared__ unsigned short obufb[64 * 264];    // 33 KB bf16 output staging (both halves), pad 8

    const int nblk = wsi[WS_NBLK];
    const int tid = threadIdx.x;
    const int lane = tid & 63, w = tid >> 6;
    const int l15 = lane & 15;
    const int kq = lane >> 4;
    const int q4 = kq * 4;
    char* lds = (char*)smem;
    f32x4 zero4; zero4[0] = zero4[1] = zero4[2] = zero4[3] = 0.f;

    for (int bi = blockIdx.x; bi < nblk; bi += NPERS) {
        const int ent = wsi[WS_TABLE + bi];
        const int e = ent >> 16;
        const int c = ent & 0xffff;
        const int start = wsi[WS_OFFSETS + e] + c * TB;
        const int cnt = min(TB, wsi[WS_OFFSETS + e + 1] - start);

        // ---- sequential xg stage loads ----
        const char* xrow = (const char*)(xg + (size_t)start * DIM);
        us8 ubuf[8];
#pragma unroll
        for (int i = 0; i < 8; ++i)
            ubuf[i] = *(const us8*)(xrow + (tid + i * 256) * 16);

        // ---- W1 register prefetch ----
        const char* w1e = (const char*)(w1t + (size_t)e * DIM * EH);
        bf16x8 b1[8][2];
#pragma unroll
        for (int ks = 0; ks < 8; ++ks)
#pragma unroll
            for (int nt = 0; nt < 2; ++nt)
                b1[ks][nt] = *(const bf16x8*)(w1e + (w * 32 + nt * 16 + l15) * 512 + ks * 64 + kq * 16);

#pragma unroll
        for (int i = 0; i < 8; ++i)
            *(us8*)(lds + SWZ9((tid + i * 256) * 16)) = ubuf[i];
        __syncthreads();   // (1) stage complete

        // ---- phase 1: C1[64 tok][32 h per wave] ----
        f32x4 acc[4][2];
#pragma unroll
        for (int i = 0; i < 4; ++i)
#pragma unroll
            for (int j = 0; j < 2; ++j) acc[i][j] = zero4;

#pragma unroll
        for (int ks = 0; ks < 8; ++ks) {
            bf16x8 a[4];
#pragma unroll
            for (int mt = 0; mt < 4; ++mt)
                a[mt] = *(const bf16x8*)(lds + SWZ9((mt * 16 + l15) * 512 + ks * 64 + kq * 16));
#pragma unroll
            for (int mt = 0; mt < 4; ++mt)
#pragma unroll
                for (int nt = 0; nt < 2; ++nt)
                    acc[mt][nt] = __builtin_amdgcn_mfma_f32_16x16x32_bf16(a[mt], b1[ks][nt], acc[mt][nt], 0, 0, 0);
        }

        // ---- prefetch phase-2 half-0 W2 fragments ----
        const char* w2e = (const char*)(w2t + (size_t)e * EH * DIM);
        bf16x8 b2a[4][2];
#pragma unroll
        for (int ks = 0; ks < 4; ++ks)
#pragma unroll
            for (int nt = 0; nt < 2; ++nt)
                b2a[ks][nt] = *(const bf16x8*)(w2e + (w * 64 + nt * 16 + l15) * 256 + ks * 64 + kq * 16);

        __syncthreads();   // (2) phase-1 LDS reads complete

        // ---- h = tanh(C1 + b1) -> hT SWZ8 ----
#pragma unroll
        for (int nt = 0; nt < 2; ++nt) {
            const int h = w * 32 + nt * 16 + l15;
            const float b1v = eb1[e * EH + h];
#pragma unroll
            for (int mt = 0; mt < 4; ++mt)
#pragma unroll
                for (int r = 0; r < 4; ++r) {
                    int tok = mt * 16 + q4 + r;
                    *(unsigned short*)(lds + SWZ8(tok * 256 + h * 2)) = f2bf(fast_tanh(acc[mt][nt][r] + b1v));
                }
        }
        __syncthreads();   // (3) hT staged

        bf16x8 b2b[4][2];
#pragma unroll
        for (int ks = 0; ks < 4; ++ks)
#pragma unroll
            for (int nt = 0; nt < 2; ++nt)
                b2b[ks][nt] = *(const bf16x8*)(w2e + (w * 64 + 32 + nt * 16 + l15) * 256 + ks * 64 + kq * 16);

        // ---- phase 2 half 0: MFMA -> obufb (cols w*64 .. w*64+31) ----
        {
            f32x4 acc2[4][2];
#pragma unroll
            for (int i = 0; i < 4; ++i)
#pragma unroll
                for (int j = 0; j < 2; ++j) acc2[i][j] = zero4;
#pragma unroll
            for (int ks = 0; ks < 4; ++ks) {
                bf16x8 a[4];
#pragma unroll
                for (int mt = 0; mt < 4; ++mt)
                    a[mt] = *(const bf16x8*)(lds + SWZ8((mt * 16 + l15) * 256 + ks * 64 + kq * 16));
#pragma unroll
                for (int mt = 0; mt < 4; ++mt)
#pragma unroll
                    for (int nt = 0; nt < 2; ++nt)
                        acc2[mt][nt] = __builtin_amdgcn_mfma_f32_16x16x32_bf16(a[mt], b2a[ks][nt], acc2[mt][nt], 0, 0, 0);
            }
            float b2v[2];
#pragma unroll
            for (int nt = 0; nt < 2; ++nt)
                b2v[nt] = eb2[e * DIM + w * 64 + nt * 16 + l15];
#pragma unroll
            for (int mt = 0; mt < 4; ++mt)
#pragma unroll
                for (int nt = 0; nt < 2; ++nt)
#pragma unroll
                    for (int r = 0; r < 4; ++r)
                        obufb[(mt * 16 + q4 + r) * 264 + w * 64 + nt * 16 + l15] =
                            f2bf(acc2[mt][nt][r] + b2v[nt]);
        }
        // ---- phase 2 half 1: MFMA -> obufb (cols w*64+32 .. w*64+63) ----
        {
            f32x4 acc2[4][2];
#pragma unroll
            for (int i = 0; i < 4; ++i)
#pragma unroll
                for (int j = 0; j < 2; ++j) acc2[i][j] = zero4;
#pragma unroll
            for (int ks = 0; ks < 4; ++ks) {
                bf16x8 a[4];
#pragma unroll
                for (int mt = 0; mt < 4; ++mt)
                    a[mt] = *(const bf16x8*)(lds + SWZ8((mt * 16 + l15) * 256 + ks * 64 + kq * 16));
#pragma unroll
                for (int mt = 0; mt < 4; ++mt)
#pragma unroll
                    for (int nt = 0; nt < 2; ++nt)
                        acc2[mt][nt] = __builtin_amdgcn_mfma_f32_16x16x32_bf16(a[mt], b2b[ks][nt], acc2[mt][nt], 0, 0, 0);
            }
            float b2v[2];
#pragma unroll
            for (int nt = 0; nt < 2; ++nt)
                b2v[nt] = eb2[e * DIM + w * 64 + 32 + nt * 16 + l15];
#pragma unroll
            for (int mt = 0; mt < 4; ++mt)
#pragma unroll
                for (int nt = 0; nt < 2; ++nt)
#pragma unroll
                    for (int r = 0; r < 4; ++r)
                        obufb[(mt * 16 + q4 + r) * 264 + w * 64 + 32 + nt * 16 + l15] =
                            f2bf(acc2[mt][nt][r] + b2v[nt]);
        }
        __syncthreads();   // (4) obufb fully staged (also guarantees all hT reads done)

        // ---- LINEAR store pass: full 512B bf16 rows, fire-and-forget ----
        {
            const int row = tid >> 2, sub = tid & 3;
            if (row < cnt) {
                const unsigned short* src = obufb + row * 264 + sub * 64;
                unsigned short* dst = out_lin + (size_t)(start + row) * DIM + sub * 64;
#pragma unroll
                for (int i = 0; i < 8; ++i)
                    *(us8*)(dst + i * 8) = *(const us8*)(src + i * 8);
            }
        }
    }
}

// ---------------- Combine: y[t] = g0*out_lin[p0] + g1*out_lin[p1] ----------------
__global__ __launch_bounds__(256) void combine_kernel(
    const unsigned short* __restrict__ out_lin,
    const int* __restrict__ wsi, const float* __restrict__ wsf,
    float* __restrict__ y)
{
    const int tid = threadIdx.x;
    const int t = blockIdx.x * 32 + (tid >> 3);
    const int sub = tid & 7;
    const int p0 = wsi[WS_INV + 2 * t + 0];
    const int p1 = wsi[WS_INV + 2 * t + 1];
    const float g0 = wsf[WS_TOKG + 2 * t + 0];
    const float g1 = wsf[WS_TOKG + 2 * t + 1];
    const unsigned short* a = out_lin + (size_t)p0 * DIM + sub * 32;
    const unsigned short* b = out_lin + (size_t)p1 * DIM + sub * 32;
    float* dst = y + (size_t)t * DIM + sub * 32;
    us8 ua[4], ub[4];
#pragma unroll
    for (int i = 0; i < 4; ++i) {
        ua[i] = *(const us8*)(a + i * 8);
        ub[i] = *(const us8*)(b + i * 8);
    }
#pragma unroll
    for (int i = 0; i < 4; ++i) {
        float4 o0, o1;
        o0.x = fmaf(g1, bf2f(ub[i][0]), g0 * bf2f(ua[i][0]));
        o0.y = fmaf(g1, bf2f(ub[i][1]), g0 * bf2f(ua[i][1]));
        o0.z = fmaf(g1, bf2f(ub[i][2]), g0 * bf2f(ua[i][2]));
        o0.w = fmaf(g1, bf2f(ub[i][3]), g0 * bf2f(ua[i][3]));
        o1.x = fmaf(g1, bf2f(ub[i][4]), g0 * bf2f(ua[i][4]));
        o1.y = fmaf(g1, bf2f(ub[i][5]), g0 * bf2f(ua[i][5]));
        o1.z = fmaf(g1, bf2f(ub[i][6]), g0 * bf2f(ua[i][6]));
        o1.w = fmaf(g1, bf2f(ub[i][7]), g0 * bf2f(ua[i][7]));
        *(float4*)(dst + i * 8) = o0;
        *(float4*)(dst + i * 8 + 4) = o1;
    }
}

extern "C" void kernel_launch(void* const* d_in, const int* in_sizes, int n_in,
                              void* d_out, int out_size, void* d_ws, size_t ws_size,
                              hipStream_t stream)
{
    const float* x = (const float*)d_in[0];
    const float* rw1 = (const float*)d_in[1];
    const float* rb1 = (const float*)d_in[2];
    const float* rw2 = (const float*)d_in[3];
    const float* rb2 = (const float*)d_in[4];
    const float* ew1 = (const float*)d_in[5];
    const float* eb1 = (const float*)d_in[6];
    const float* ew2 = (const float*)d_in[7];
    const float* eb2 = (const float*)d_in[8];

    float* y = (float*)d_out;                       // [NT][DIM]
    float* w_out = y + (size_t)NT * DIM;            // [NT][NE]
    int* wsi = (int*)d_ws;
    float* wsf = (float*)d_ws;
    unsigned short* wsu = (unsigned short*)d_ws;

    hipMemsetAsync(wsi + WS_COUNTS, 0, NE * sizeof(int), stream);

    wprep_kernel<<<256, 256, 0, stream>>>(ew1, ew2, wsu + U_W1T, wsu + U_W2T);
    router_kernel<<<NT / 64, 256, 0, stream>>>(x, rw1, rb1, rw2, rb2, w_out, wsi, wsf);
    scan_kernel<<<1, 64, 0, stream>>>(wsi);
    scatter_kernel<<<NT / 256, 256, 0, stream>>>(wsi);
    gather_kernel<<<2 * NT / 32, 256, 0, stream>>>(x, wsi, wsu + U_XG);
    expert_kernel<<<NPERS, 256, 0, stream>>>(wsu + U_XG, eb1, eb2,
                                             wsu + U_W1T, wsu + U_W2T,
                                             wsi, wsu + U_OUT);
    combine_kernel<<<NT / 32, 256, 0, stream>>>(wsu + U_OUT, wsi, wsf, y);
}